// Round 2
// baseline (333.199 us; speedup 1.0000x reference)
//
#include <hip/hip_runtime.h>
#include <hip/hip_bf16.h>

#define BB 16
#define C 128
#define HW 4096
#define NPOS 65536   // BB*HW
#define K 1024
#define NT 64        // positions per block
#define KT 64        // codes per chunk
#define NCHUNK (K / KT)

// fp32 element offsets into d_out (flat concat, reference return order)
#define ZQ_OFF 0
#define LOSS_OFF 8388608
#define IDX_OFF 8388609
#define COMMIT_OFF 8454145
#define CODE_OFF 8454146

__global__ void vq_enorm(const float* __restrict__ emb, float* __restrict__ enorm) {
    int k = blockIdx.x * 4 + (threadIdx.x >> 6);
    int l = threadIdx.x & 63;
    const float* row = emb + (size_t)k * C;
    float v = row[l] * row[l] + row[l + 64] * row[l + 64];
    #pragma unroll
    for (int off = 32; off; off >>= 1) v += __shfl_down(v, off);
    if (l == 0) enorm[k] = v;
}

__global__ __launch_bounds__(256, 2)
void vq_main(const float* __restrict__ z, const float* __restrict__ emb,
             const float* __restrict__ enorm, float* __restrict__ out,
             float* __restrict__ S) {
    __shared__ float zt[C * NT];        // [c][i], 32 KB
    __shared__ float et[C * KT];        // [c][kk], 32 KB
    __shared__ float red_s[NT * 16];    // 4 KB
    __shared__ int   red_i[NT * 16];    // 4 KB
    __shared__ int   final_idx[NT];
    __shared__ float wsum[4];

    const int t = threadIdx.x;
    const int blk = blockIdx.x;
    const int n0 = blk * NT;
    const int b = n0 / HW;
    const int hw0 = n0 % HW;
    const float* zbase = z + (size_t)b * C * HW + hw0;   // (c,i) at zbase[c*HW + i]

    // stage z tile: [c][i], coalesced 64-float rows
    #pragma unroll
    for (int j = 0; j < C * NT / 256; ++j) {
        int flat = j * 256 + t;
        int c = flat >> 6, i = flat & 63;
        zt[c * NT + i] = zbase[c * HW + i];
    }

    const int ti = t & 15;   // position group: positions ti*4 .. ti*4+3
    const int tk = t >> 4;   // code group:     codes    tk*4 .. tk*4+3 within chunk

    float best_s[4] = {1e30f, 1e30f, 1e30f, 1e30f};
    int   best_i[4] = {0, 0, 0, 0};

    for (int ch = 0; ch < NCHUNK; ++ch) {
        const int k0 = ch * KT;
        __syncthreads();   // prev chunk's reads of et done (also covers z staging at ch=0)
        // stage codes transposed: et[c][kk] = emb[k0+kk][c]; lane = kk
        {
            int lane = t & 63, wv = t >> 6;
            const float4* erow = (const float4*)(emb + (size_t)(k0 + lane) * C);
            for (int q = wv; q < C / 4; q += 4) {
                float4 v = erow[q];
                et[(q * 4 + 0) * KT + lane] = v.x;
                et[(q * 4 + 1) * KT + lane] = v.y;
                et[(q * 4 + 2) * KT + lane] = v.z;
                et[(q * 4 + 3) * KT + lane] = v.w;
            }
        }
        __syncthreads();

        float acc[4][4] = {{0.f}};
        #pragma unroll 4
        for (int c = 0; c < C; ++c) {
            float4 zv = *(const float4*)&zt[c * NT + ti * 4];
            float4 ev = *(const float4*)&et[c * KT + tk * 4];
            float zr[4] = {zv.x, zv.y, zv.z, zv.w};
            float er[4] = {ev.x, ev.y, ev.z, ev.w};
            #pragma unroll
            for (int ii = 0; ii < 4; ++ii)
                #pragma unroll
                for (int kk = 0; kk < 4; ++kk)
                    acc[ii][kk] = fmaf(zr[ii], er[kk], acc[ii][kk]);
        }
        #pragma unroll
        for (int kk = 0; kk < 4; ++kk) {
            int kidx = k0 + tk * 4 + kk;
            float en = enorm[kidx];
            #pragma unroll
            for (int ii = 0; ii < 4; ++ii) {
                float s = en - 2.f * acc[ii][kk];
                if (s < best_s[ii]) { best_s[ii] = s; best_i[ii] = kidx; }
            }
        }
    }

    __syncthreads();
    #pragma unroll
    for (int ii = 0; ii < 4; ++ii) {
        int i = ti * 4 + ii;
        red_s[i * 16 + tk] = best_s[ii];
        red_i[i * 16 + tk] = best_i[ii];
    }
    __syncthreads();
    if (t < NT) {
        int i = t;
        float bs = red_s[i * 16];
        int bi = red_i[i * 16];
        #pragma unroll
        for (int m = 1; m < 16; ++m) {
            float s = red_s[i * 16 + m];
            int ix = red_i[i * 16 + m];
            if (s < bs || (s == bs && ix < bi)) { bs = s; bi = ix; }
        }
        final_idx[i] = bi;
        out[IDX_OFF + n0 + i] = (float)bi;
    }
    __syncthreads();

    // gather z_q, write fp32, accumulate loss
    float ls = 0.f;
    #pragma unroll
    for (int j = 0; j < C * NT / 256; ++j) {
        int flat = j * 256 + t;
        int c = flat >> 6, i = flat & 63;
        float zv = zt[c * NT + i];
        float ev = emb[(size_t)final_idx[i] * C + c];
        float d = zv - ev;
        ls += d * d;
        out[ZQ_OFF + (size_t)(b * C + c) * HW + hw0 + i] = ev;
    }
    #pragma unroll
    for (int off = 32; off; off >>= 1) ls += __shfl_down(ls, off);
    if ((t & 63) == 0) wsum[t >> 6] = ls;
    __syncthreads();
    if (t == 0) atomicAdd(S, wsum[0] + wsum[1] + wsum[2] + wsum[3]);
}

__global__ void vq_final(const float* __restrict__ S, float* __restrict__ out) {
    float s = *S;
    out[LOSS_OFF]   = 1.25f * s;
    out[COMMIT_OFF] = 0.25f * s;
    out[CODE_OFF]   = s;
}

extern "C" void kernel_launch(void* const* d_in, const int* in_sizes, int n_in,
                              void* d_out, int out_size, void* d_ws, size_t ws_size,
                              hipStream_t stream) {
    const float* z = (const float*)d_in[0];
    const float* emb = (const float*)d_in[1];
    float* out = (float*)d_out;
    float* S = (float*)d_ws;                 // [0]: loss accumulator
    float* enorm = (float*)d_ws + 16;        // byte offset 64: K floats

    hipMemsetAsync(d_ws, 0, 64, stream);     // zero the accumulator (ws re-poisoned 0xAA)
    vq_enorm<<<K / 4, 256, 0, stream>>>(emb, enorm);
    vq_main<<<NPOS / NT, 256, 0, stream>>>(z, emb, enorm, out, S);
    vq_final<<<1, 1, 0, stream>>>(S, out);
}

// Round 3
// 118.502 us; speedup vs baseline: 2.8118x; 2.8118x over previous
//
#include <hip/hip_runtime.h>
#include <hip/hip_bf16.h>

#define C 128
#define HW 4096
#define NPOS 65536
#define K 1024
#define MB 128           // positions per block
#define NBLK (NPOS/MB)   // 512
#define RS 136           // padded row stride in bf16 elems (272 B)
#define RSB 272          // row stride bytes
#define CHK 64           // codes per chunk
#define NCH (K/CHK)      // 16
#define CHB (CHK*RSB)    // 17408 bytes per chunk

#define ZQ_OFF 0
#define LOSS_OFF 8388608
#define IDX_OFF 8388609
#define COMMIT_OFF 8454145
#define CODE_OFF 8454146

#define WS_IMG_OFF 8192  // bf16 codebook image at d_ws + 8192, 1024*272 B

typedef __bf16 bf16x8 __attribute__((ext_vector_type(8)));
typedef float f32x4 __attribute__((ext_vector_type(4)));

// Build padded bf16 codebook image: row k = 128 bf16 (272B stride),
// fp32 (||e_k||^2 + 1.0) stored at row byte offset 256 (in the pad).
__global__ void vq_prep(const float* __restrict__ emb, unsigned char* __restrict__ img) {
    int k = blockIdx.x;
    int l = threadIdx.x;            // 64 threads
    float v0 = emb[k * C + l];
    float v1 = emb[k * C + 64 + l];
    __hip_bfloat16 h0 = __float2bfloat16(v0);
    __hip_bfloat16 h1 = __float2bfloat16(v1);
    unsigned short* row = (unsigned short*)(img + (size_t)k * RSB);
    row[l] = *(unsigned short*)&h0;
    row[64 + l] = *(unsigned short*)&h1;
    float s = v0 * v0 + v1 * v1;
    #pragma unroll
    for (int off = 32; off; off >>= 1) s += __shfl_down(s, off);
    if (l == 0) *(float*)(img + (size_t)k * RSB + 256) = s + 1.0f;
}

__global__ __launch_bounds__(256, 2)
void vq_main(const float* __restrict__ z, const float* __restrict__ emb,
             const unsigned char* __restrict__ img,
             float* __restrict__ out, float* __restrict__ S) {
    __shared__ unsigned short zt[MB * RS];        // 34816 B, z tile bf16, padded rows
    __shared__ unsigned short bbuf[2][CHK * RS];  // 2 x 17408 B, codebook chunks
    __shared__ unsigned int wbest[4][MB];         // 2048 B
    __shared__ unsigned short idxs[MB];           // 256 B
    __shared__ float lred[4];

    const int t = threadIdx.x;
    const int w = t >> 6;
    const int lane = t & 63;
    const int nn = lane & 15;      // MFMA: A row m / B col n / C col
    const int q = lane >> 4;       // quad

    const int blk = blockIdx.x;
    const int n0g = blk * MB;
    const int b = n0g >> 12;
    const int hw0 = n0g & (HW - 1);
    const float* zg = z + (size_t)b * C * HW + hw0;

    // async stage chunk 0 of codebook image (17 x 1KB, split across waves)
    for (int j = w; j < 17; j += 4) {
        __builtin_amdgcn_global_load_lds(
            (const __attribute__((address_space(1))) unsigned int*)(img + j * 1024 + lane * 16),
            (__attribute__((address_space(3))) unsigned int*)((unsigned char*)bbuf[0] + j * 1024),
            16, 0, 0);
    }

    // stage z tile -> LDS bf16 [pos][c], row stride 272B
    {
        int pos = t & (MB - 1);
        int c0b = (t >> 7) * 64;
        #pragma unroll
        for (int i = 0; i < 16; ++i) {
            int c0 = c0b + i * 4;
            float f0 = zg[(size_t)(c0 + 0) * HW + pos];
            float f1 = zg[(size_t)(c0 + 1) * HW + pos];
            float f2 = zg[(size_t)(c0 + 2) * HW + pos];
            float f3 = zg[(size_t)(c0 + 3) * HW + pos];
            __hip_bfloat16 h0 = __float2bfloat16(f0), h1 = __float2bfloat16(f1),
                           h2 = __float2bfloat16(f2), h3 = __float2bfloat16(f3);
            ushort4 pk;
            pk.x = *(unsigned short*)&h0; pk.y = *(unsigned short*)&h1;
            pk.z = *(unsigned short*)&h2; pk.w = *(unsigned short*)&h3;
            *(ushort4*)&zt[pos * RS + c0] = pk;
        }
    }
    __syncthreads();   // covers zt ds_writes AND chunk-0 global_load_lds (vmcnt drain)

    // A fragments in registers: 8 M-tiles x 4 K-steps, reused across ALL codes
    bf16x8 a[8][4];
    #pragma unroll
    for (int mt = 0; mt < 8; ++mt)
        #pragma unroll
        for (int ks = 0; ks < 4; ++ks)
            a[mt][ks] = *(bf16x8*)&zt[(mt * 16 + nn) * RS + ks * 32 + q * 8];

    unsigned int best[8][4];
    #pragma unroll
    for (int mt = 0; mt < 8; ++mt)
        #pragma unroll
        for (int r = 0; r < 4; ++r) best[mt][r] = 0xFFFFFFFFu;

    for (int ch = 0; ch < NCH; ++ch) {
        const int p = ch & 1;
        if (ch + 1 < NCH) {   // prefetch next chunk into other buffer
            const unsigned char* src = img + (size_t)(ch + 1) * CHB;
            for (int j = w; j < 17; j += 4) {
                __builtin_amdgcn_global_load_lds(
                    (const __attribute__((address_space(1))) unsigned int*)(src + j * 1024 + lane * 16),
                    (__attribute__((address_space(3))) unsigned int*)((unsigned char*)bbuf[p ^ 1] + j * 1024),
                    16, 0, 0);
            }
        }
        const unsigned short* bb = bbuf[p];
        const int row = w * 16 + nn;          // wave w owns 16 codes of this chunk
        bf16x8 bf[4];
        #pragma unroll
        for (int ks = 0; ks < 4; ++ks)
            bf[ks] = *(bf16x8*)&bb[row * RS + ks * 32 + q * 8];
        const float en1 = *(const float*)&bb[row * RS + 128];   // ||e||^2 + 1 (fp32)
        const unsigned int code = (unsigned int)(ch * CHK + row);

        f32x4 acc[8];
        #pragma unroll
        for (int mt = 0; mt < 8; ++mt) acc[mt] = (f32x4){0.f, 0.f, 0.f, 0.f};
        #pragma unroll
        for (int ks = 0; ks < 4; ++ks)
            #pragma unroll
            for (int mt = 0; mt < 8; ++mt)
                acc[mt] = __builtin_amdgcn_mfma_f32_16x16x32_bf16(a[mt][ks], bf[ks], acc[mt], 0, 0, 0);

        // packed argmin: score' = (enorm+1) - 2*dot  (always in (0.68,1.32) > 0),
        // clear low 10 mantissa bits, OR in code; u32 min == float min + tie-low.
        #pragma unroll
        for (int mt = 0; mt < 8; ++mt)
            #pragma unroll
            for (int r = 0; r < 4; ++r) {
                float s = fmaf(acc[mt][r], -2.0f, en1);
                unsigned int u = (__float_as_uint(s) & ~1023u) | code;
                best[mt][r] = min(best[mt][r], u);
            }
        __syncthreads();   // chunk consumed by all waves; prefetched data now visible
    }

    // in-wave reduce over the 16 code-columns (xor lanes 1,2,4,8 stay in quad)
    #pragma unroll
    for (int mt = 0; mt < 8; ++mt)
        #pragma unroll
        for (int r = 0; r < 4; ++r) {
            unsigned int v = best[mt][r];
            v = min(v, (unsigned int)__shfl_xor((int)v, 1));
            v = min(v, (unsigned int)__shfl_xor((int)v, 2));
            v = min(v, (unsigned int)__shfl_xor((int)v, 4));
            v = min(v, (unsigned int)__shfl_xor((int)v, 8));
            if (nn == 0) wbest[w][mt * 16 + q * 4 + r] = v;   // pos-local
        }
    __syncthreads();

    if (t < MB) {
        unsigned int v = min(min(wbest[0][t], wbest[1][t]), min(wbest[2][t], wbest[3][t]));
        unsigned int code = v & 1023u;
        idxs[t] = (unsigned short)code;
        out[IDX_OFF + n0g + t] = (float)code;
    }
    __syncthreads();

    // epilogue: exact fp32 gather of chosen code rows, z_q store, loss
    {
        int pos = t & (MB - 1);
        int c0b = (t >> 7) * 64;
        int myidx = idxs[pos];
        const float* erow = emb + (size_t)myidx * C;
        float* og = out + ZQ_OFF + (size_t)b * C * HW + hw0;
        float ls = 0.f;
        #pragma unroll
        for (int i = 0; i < 16; ++i) {
            int c0 = c0b + i * 4;
            float4 ev = *(const float4*)&erow[c0];
            ushort4 zz = *(ushort4*)&zt[pos * RS + c0];
            float z0 = __uint_as_float((unsigned int)zz.x << 16);
            float z1 = __uint_as_float((unsigned int)zz.y << 16);
            float z2 = __uint_as_float((unsigned int)zz.z << 16);
            float z3 = __uint_as_float((unsigned int)zz.w << 16);
            float d0 = z0 - ev.x, d1 = z1 - ev.y, d2 = z2 - ev.z, d3 = z3 - ev.w;
            ls += d0 * d0 + d1 * d1 + d2 * d2 + d3 * d3;
            og[(size_t)(c0 + 0) * HW + pos] = ev.x;
            og[(size_t)(c0 + 1) * HW + pos] = ev.y;
            og[(size_t)(c0 + 2) * HW + pos] = ev.z;
            og[(size_t)(c0 + 3) * HW + pos] = ev.w;
        }
        #pragma unroll
        for (int off = 32; off; off >>= 1) ls += __shfl_down(ls, off);
        if (lane == 0) lred[w] = ls;
    }
    __syncthreads();
    if (t == 0) atomicAdd(S, lred[0] + lred[1] + lred[2] + lred[3]);
}

__global__ void vq_final(const float* __restrict__ S, float* __restrict__ out) {
    float s = *S;
    out[LOSS_OFF] = 1.25f * s;
    out[COMMIT_OFF] = 0.25f * s;
    out[CODE_OFF] = s;
}

extern "C" void kernel_launch(void* const* d_in, const int* in_sizes, int n_in,
                              void* d_out, int out_size, void* d_ws, size_t ws_size,
                              hipStream_t stream) {
    const float* z = (const float*)d_in[0];
    const float* emb = (const float*)d_in[1];
    float* out = (float*)d_out;
    float* S = (float*)d_ws;
    unsigned char* img = (unsigned char*)d_ws + WS_IMG_OFF;   // needs ~287 KB of ws

    hipMemsetAsync(d_ws, 0, 64, stream);
    vq_prep<<<K, 64, 0, stream>>>(emb, img);
    vq_main<<<NBLK, 256, 0, stream>>>(z, emb, img, out, S);
    vq_final<<<1, 1, 0, stream>>>(S, out);
}